// Round 8
// baseline (4451.512 us; speedup 1.0000x reference)
//
#include <hip/hip_runtime.h>
#include <stdint.h>

// v7 (resubmit — round-7 bench was an infra flake, kernel never ran).
// LDS-pipe + weight-traffic fix on v6.
//  - 2 samples processed SEQUENTIALLY per block (same 40,448B pool reused;
//    existing barriers order the reuse) -> halves per-sample L2 weight reads.
//  - s10 co-QUAD (2 wave-streams of ds instead of 4), merged-s8 all-3h per
//    thread (v2-proven, ds 4050->2550/block). ds instruction streams are
//    per-wave; fewer waves running the loop = fewer LDS-pipe cycles.
//  - Wave-rotation of partial phases: task index q = (tid - rot) & 255 with
//    rot = ((blockIdx+si)&3)<<6, so the 4 resident blocks' active waves land
//    on different SIMDs (without it, co-quad pins all work on SIMD0/1).

#define WB2T_OFF 0        // w0b2: [k=ci*2+dh][512], 600*512 = 307200
#define WC2T_OFF 307200   // w0c2: [k=ci*3+dh][512], 375*512 = 192000
#define W0T_OFF  499200   // w0:   [k=ci*2+dh][300], 250*300 = 75000
#define W1T_OFF  574200   // w1:   [k=ci*2+dh][75],   50*75  = 3750
#define WAT_OFF  577950   // wa:   [k=ci*3+dh][125],  75*125 = 9375
#define W2T_OFF  587325   // w2:   [k=ci*2+dh][125], 150*125 = 18750
#define WT_TOTAL 606075

__global__ __launch_bounds__(256)
void transpose_w(const float* __restrict__ w1, const float* __restrict__ wa,
                 const float* __restrict__ w2, const float* __restrict__ w0,
                 const float* __restrict__ wb2, const float* __restrict__ wc2,
                 float* __restrict__ ws) {
  int i = blockIdx.x * 256 + threadIdx.x;
  if (i < 3750) {                      // w1: M=75,  K=50
    int co = i / 50, k = i % 50;
    ws[W1T_OFF + k*75 + co] = w1[i];
  } else if (i < 13125) {              // wa: M=125, K=75
    int j = i - 3750; int co = j / 75, k = j % 75;
    ws[WAT_OFF + k*125 + co] = wa[j];
  } else if (i < 31875) {              // w2: M=125, K=150
    int j = i - 13125; int co = j / 150, k = j % 150;
    ws[W2T_OFF + k*125 + co] = w2[j];
  } else if (i < 106875) {             // w0: M=300, K=250
    int j = i - 31875; int co = j / 250, k = j % 250;
    ws[W0T_OFF + k*300 + co] = w0[j];
  } else if (i < 414075) {             // w0b2: M=512, K=600
    int j = i - 106875; int co = j / 600, k = j % 600;
    ws[WB2T_OFF + k*512 + co] = wb2[j];
  } else if (i < 606075) {             // w0c2: M=512, K=375
    int j = i - 414075; int co = j / 375, k = j % 375;
    ws[WC2T_OFF + k*512 + co] = wc2[j];
  }
}

template<int N>
__device__ __forceinline__ void ldrow(float* r, const float* p) {
  #pragma unroll
  for (int i = 0; i < N/4; ++i) {
    float4 q = reinterpret_cast<const float4*>(p)[i];
    r[4*i+0] = q.x; r[4*i+1] = q.y; r[4*i+2] = q.z; r[4*i+3] = q.w;
  }
}
template<int N>
__device__ __forceinline__ void strow(float* p, const float* r) {
  #pragma unroll
  for (int i = 0; i < N/4; ++i) {
    float4 q; q.x = r[4*i+0]; q.y = r[4*i+1]; q.z = r[4*i+2]; q.w = r[4*i+3];
    reinterpret_cast<float4*>(p)[i] = q;
  }
}

// Single-sample LDS pool (floats). All offsets & strides multiples of 4.
#define POOL   10112   // 40,448 B -> 4 blocks/CU by LDS
#define X1_O   0
#define SX_O   2500
#define Z0A_O  2640
#define Z0SL_O 4500
#define T90_O  5000
#define Z1S_O  4500
#define T2_O   8100
#define X2_O   0
#define T3_O   4500
#define Z2S_O  6500

__global__ __launch_bounds__(256, 3)
void fused_net(const float* __restrict__ xg,
  const float* __restrict__ w0a_, const float* __restrict__ b0a_,
  const float* __restrict__ wl0_, const float* __restrict__ bl0_,
  const float* __restrict__ w0b_, const float* __restrict__ b0b_,
  const float* __restrict__ w0c_, const float* __restrict__ b0c_,
  const float* __restrict__ wr0_, const float* __restrict__ br0_,
  const float* __restrict__ b1_,
  const float* __restrict__ wl1_, const float* __restrict__ bl1_,
  const float* __restrict__ b2_,
  const float* __restrict__ ba_,
  const float* __restrict__ wra_, const float* __restrict__ bra_,
  const float* __restrict__ b0_,
  const float* __restrict__ wl2_, const float* __restrict__ bl2_,
  const float* __restrict__ b0b2_,
  const float* __restrict__ b0c2_,
  const float* __restrict__ wr02_,const float* __restrict__ br02_,
  const float* __restrict__ w1t, const float* __restrict__ wat,
  const float* __restrict__ w2t, const float* __restrict__ w0t,
  const float* __restrict__ wb2t, const float* __restrict__ wc2t,
  float* __restrict__ outg, int Btot)
{
  __shared__ __align__(16) float P[POOL];   // 40,448 B
  const int tid = threadIdx.x;

  #pragma unroll 1
  for (int si = 0; si < 2; ++si) {
    const int b = blockIdx.x * 2 + si;
    if (b >= Btot) break;
    const int rot = ((blockIdx.x + si) & 3) << 6;
    const int q = (tid + 256 - rot) & 255;   // rotated task index

    // ---- s1: load x (5h,27w) -> SX stride 28
    if (q < 135) {
      int h = q / 27, w = q % 27;
      P[SX_O + h*28 + w] = xg[(size_t)b * 135 + q];
    }
    __syncthreads();

    // ---- s2: Z0A = conv w0a (1->5, kh=3, ph=1). 25 tasks = (co,h).
    if (q < 25) {
      int co = q / 5, h = q % 5;
      float acc[28];
      float bias = b0a_[co];
      #pragma unroll
      for (int w = 0; w < 28; ++w) acc[w] = bias;
      #pragma unroll
      for (int dh = 0; dh < 3; ++dh) {
        int hi = h + dh - 1;
        if (hi >= 0 && hi < 5) {
          float wf = w0a_[co*3 + dh];
          float row[28]; ldrow<28>(row, P + SX_O + hi*28);
          #pragma unroll
          for (int w = 0; w < 27; ++w) acc[w] += row[w] * wf;
        }
      }
      strow<28>(P + Z0A_O + (co*5 + h)*28, acc);
    }
    __syncthreads();

    // ---- {s3|s4}: Z0SL = relu(sl(Z0A,wl0)) [75]; T90 = sl(SX,wr0) [15].
    if (q < 90) {
      if (q < 75) {
        int c = q / 15, r = q % 15, h = r / 3, o0 = (r % 3) * 6;
        float row[28]; ldrow<28>(row, P + Z0A_O + (c*5 + h)*28);
        float acc[6];
        #pragma unroll
        for (int k = 0; k < 6; ++k) acc[k] = bl0_[o0 + k];
        for (int w = 0; w < 27; ++w) {
          float rv = row[w];
          #pragma unroll
          for (int k = 0; k < 6; ++k) acc[k] += rv * wl0_[(o0 + k)*27 + w];
        }
        float* dst = P + Z0SL_O + (c*5 + h)*20 + o0;
        #pragma unroll
        for (int k = 0; k < 6; ++k) dst[k] = fmaxf(acc[k], 0.f);
      } else {
        int r = q - 75, h = r / 3, o0 = (r % 3) * 6;
        float row[28]; ldrow<28>(row, P + SX_O + h*28);
        float acc[6];
        #pragma unroll
        for (int k = 0; k < 6; ++k) acc[k] = br0_[o0 + k];
        for (int w = 0; w < 27; ++w) {
          float rv = row[w];
          #pragma unroll
          for (int k = 0; k < 6; ++k) acc[k] += rv * wr0_[(o0 + k)*27 + w];
        }
        float* dst = P + T90_O + h*20 + o0;
        #pragma unroll
        for (int k = 0; k < 6; ++k) dst[k] = acc[k];
      }
    }
    __syncthreads();

    // ---- s5: X1 = conv w0b(Z0SL) + b0b + (w0c*T90 + b0c). 125 tasks = (h,co).
    if (q < 125) {
      int h = q / 25, co = q % 25;
      float tr[20]; ldrow<20>(tr, P + T90_O + h*20);
      float wc = w0c_[co];
      float base = b0b_[co] + b0c_[co];
      float acc[20];
      #pragma unroll
      for (int o = 0; o < 18; ++o) acc[o] = base + tr[o]*wc;
      acc[18] = 0.f; acc[19] = 0.f;
      #pragma unroll
      for (int dh = 0; dh < 3; ++dh) {
        int hi = h + dh - 1;
        if (hi >= 0 && hi < 5) {
          #pragma unroll
          for (int ci = 0; ci < 5; ++ci) {
            float wgt = w0b_[(co*5 + ci)*3 + dh];
            float row[20]; ldrow<20>(row, P + Z0SL_O + (ci*5 + hi)*20);
            #pragma unroll
            for (int o = 0; o < 18; ++o) acc[o] += row[o] * wgt;
          }
        }
      }
      strow<20>(P + X1_O + (co*5 + h)*20, acc);
    }
    __syncthreads();

    // ---- {s7|s6}: both read X1 only; disjoint writes (Z1S / T2). 425 tasks.
    for (int t = q; t < 425; t += 256) {
      if (t < 300) {
        // s7: Z1S = relu(sl(conv w1(X1), wl1)). (h,co).
        int h = t / 75, co = t % 75;
        float z1[18];
        float bias = b1_[co];
        #pragma unroll
        for (int w = 0; w < 18; ++w) z1[w] = bias;
        for (int ci = 0; ci < 25; ++ci) {
          float wx = w1t[(ci*2 + 0)*75 + co];
          float wy = w1t[(ci*2 + 1)*75 + co];
          float r0[20], r1[20];
          ldrow<20>(r0, P + X1_O + (ci*5 + h    )*20);
          ldrow<20>(r1, P + X1_O + (ci*5 + h + 1)*20);
          #pragma unroll
          for (int w = 0; w < 18; ++w) z1[w] += r0[w]*wx + r1[w]*wy;
        }
        float out[12];
        #pragma unroll
        for (int o = 0; o < 10; ++o) {
          float acc = bl1_[o];
          #pragma unroll
          for (int w = 0; w < 18; ++w) acc += z1[w] * wl1_[o*18 + w];
          out[o] = fmaxf(acc, 0.f);
        }
        out[10] = 0.f; out[11] = 0.f;
        strow<12>(P + Z1S_O + (co*4 + h)*12, out);
      } else {
        // s6: T2 = sl(X1, wra). 125 tasks = (h,c).
        int r = t - 300;
        int h = r / 25, c = r % 25;
        float row[20]; ldrow<20>(row, P + X1_O + (c*5 + h)*20);
        float out[12];
        #pragma unroll
        for (int o = 0; o < 10; ++o) {
          float acc = bra_[o];
          #pragma unroll
          for (int w = 0; w < 18; ++w) acc += row[w] * wra_[o*18 + w];
          out[o] = acc;
        }
        out[10] = 0.f; out[11] = 0.f;
        strow<12>(P + T2_O + (c*5 + h)*12, out);
      }
    }
    __syncthreads();

    // ---- merged s6.5+s8: X2 = conv wa(T2) + conv w2(Z1S) + b2 + ba.
    //      125 tasks = co; each thread computes all 3 h rows.
    if (q < 125) {
      int co = q;
      float acc[3][10];
      float bias = b2_[co] + ba_[co];
      #pragma unroll
      for (int h = 0; h < 3; ++h)
        #pragma unroll
        for (int w = 0; w < 10; ++w) acc[h][w] = bias;
      for (int ci = 0; ci < 25; ++ci) {          // conv wa over T2 (kh=3)
        float wf0 = wat[(ci*3 + 0)*125 + co];
        float wf1 = wat[(ci*3 + 1)*125 + co];
        float wf2 = wat[(ci*3 + 2)*125 + co];
        float rr[5][12];
        #pragma unroll
        for (int hh = 0; hh < 5; ++hh) ldrow<12>(rr[hh], P + T2_O + (ci*5 + hh)*12);
        #pragma unroll
        for (int h = 0; h < 3; ++h)
          #pragma unroll
          for (int w = 0; w < 10; ++w)
            acc[h][w] += rr[h][w]*wf0 + rr[h+1][w]*wf1 + rr[h+2][w]*wf2;
      }
      for (int ci = 0; ci < 75; ++ci) {          // conv w2 over Z1S (kh=2)
        float wx = w2t[(ci*2 + 0)*125 + co];
        float wy = w2t[(ci*2 + 1)*125 + co];
        float rr[4][12];
        #pragma unroll
        for (int hh = 0; hh < 4; ++hh) ldrow<12>(rr[hh], P + Z1S_O + (ci*4 + hh)*12);
        #pragma unroll
        for (int h = 0; h < 3; ++h)
          #pragma unroll
          for (int w = 0; w < 10; ++w)
            acc[h][w] += rr[h][w]*wx + rr[h+1][w]*wy;
      }
      #pragma unroll
      for (int h = 0; h < 3; ++h) {
        float out[12];
        #pragma unroll
        for (int w = 0; w < 10; ++w) out[w] = acc[h][w];
        out[10] = 0.f; out[11] = 0.f;
        strow<12>(P + X2_O + (co*3 + h)*12, out);
      }
    }
    __syncthreads();

    // ---- {s9|s8.5}: both read X2 only; disjoint writes. 150+63 = 213 tasks.
    if (q < 150) {
      // s9: Z2S = relu(sl(conv w0(X2), wl2)). co-PAIR per thread (f2 weights).
      int co = q * 2;
      float acc[2][2][10];
      #pragma unroll
      for (int j = 0; j < 2; ++j) {
        float bb = b0_[co + j];
        #pragma unroll
        for (int h = 0; h < 2; ++h)
          #pragma unroll
          for (int w = 0; w < 10; ++w) acc[j][h][w] = bb;
      }
      for (int ci = 0; ci < 125; ++ci) {
        float a0[12], a1[12], a2[12];
        ldrow<12>(a0, P + X2_O + (ci*3 + 0)*12);
        ldrow<12>(a1, P + X2_O + (ci*3 + 1)*12);
        ldrow<12>(a2, P + X2_O + (ci*3 + 2)*12);
        float2 wxv = *reinterpret_cast<const float2*>(w0t + (ci*2 + 0)*300 + co);
        float2 wyv = *reinterpret_cast<const float2*>(w0t + (ci*2 + 1)*300 + co);
        float wx[2] = {wxv.x, wxv.y};
        float wy[2] = {wyv.x, wyv.y};
        #pragma unroll
        for (int j = 0; j < 2; ++j)
          #pragma unroll
          for (int w = 0; w < 10; ++w) {
            acc[j][0][w] += a0[w]*wx[j] + a1[w]*wy[j];
            acc[j][1][w] += a1[w]*wx[j] + a2[w]*wy[j];
          }
      }
      #pragma unroll
      for (int j = 0; j < 2; ++j) {
        float out[12];
        #pragma unroll
        for (int h = 0; h < 2; ++h)
          #pragma unroll
          for (int o = 0; o < 5; ++o) {
            float sacc = bl2_[o];
            #pragma unroll
            for (int w = 0; w < 10; ++w) sacc += acc[j][h][w] * wl2_[o*10 + w];
            out[h*5 + o] = fmaxf(sacc, 0.f);
          }
        out[10] = 0.f; out[11] = 0.f;
        strow<12>(P + Z2S_O + (co + j)*12, out);
      }
    } else if (q < 213) {
      // s8.5: T3 = sl(X2, wr02). 63 tasks x 2 channels.
      int r = q - 150;
      #pragma unroll
      for (int cc = 0; cc < 2; ++cc) {
        int c = r*2 + cc;
        if (c < 125) {
          float rr[3][12];
          #pragma unroll
          for (int h = 0; h < 3; ++h) ldrow<12>(rr[h], P + X2_O + (c*3 + h)*12);
          float out[16];
          #pragma unroll
          for (int h = 0; h < 3; ++h)
            #pragma unroll
            for (int o = 0; o < 5; ++o) {
              float acc = br02_[o];
              #pragma unroll
              for (int w = 0; w < 10; ++w) acc += rr[h][w] * wr02_[o*10 + w];
              out[h*5 + o] = acc;
            }
          out[15] = 0.f;
          strow<16>(P + T3_O + c*16, out);
        }
      }
    }
    __syncthreads();

    // ---- s10: out = conv w0b2(Z2S) + conv w0c2(T3). 128 tasks = co-QUAD.
    if (q < 128) {
      int co = q * 4;
      float acc[4][5];
      #pragma unroll
      for (int j = 0; j < 4; ++j) {
        float bb = b0b2_[co + j] + b0c2_[co + j];
        #pragma unroll
        for (int w = 0; w < 5; ++w) acc[j][w] = bb;
      }
      for (int ci = 0; ci < 300; ++ci) {          // w0b2: kh=2
        float a[12]; ldrow<12>(a, P + Z2S_O + ci*12);
        float4 uxv = *reinterpret_cast<const float4*>(wb2t + (ci*2 + 0)*512 + co);
        float4 uyv = *reinterpret_cast<const float4*>(wb2t + (ci*2 + 1)*512 + co);
        float ux[4] = {uxv.x, uxv.y, uxv.z, uxv.w};
        float uy[4] = {uyv.x, uyv.y, uyv.z, uyv.w};
        #pragma unroll
        for (int j = 0; j < 4; ++j)
          #pragma unroll
          for (int w = 0; w < 5; ++w)
            acc[j][w] += a[w]*ux[j] + a[5 + w]*uy[j];
      }
      for (int ci = 0; ci < 125; ++ci) {          // w0c2: kh=3
        float t3[16]; ldrow<16>(t3, P + T3_O + ci*16);
        float4 u0v = *reinterpret_cast<const float4*>(wc2t + (ci*3 + 0)*512 + co);
        float4 u1v = *reinterpret_cast<const float4*>(wc2t + (ci*3 + 1)*512 + co);
        float4 u2v = *reinterpret_cast<const float4*>(wc2t + (ci*3 + 2)*512 + co);
        float u0[4] = {u0v.x, u0v.y, u0v.z, u0v.w};
        float u1[4] = {u1v.x, u1v.y, u1v.z, u1v.w};
        float u2[4] = {u2v.x, u2v.y, u2v.z, u2v.w};
        #pragma unroll
        for (int j = 0; j < 4; ++j)
          #pragma unroll
          for (int w = 0; w < 5; ++w)
            acc[j][w] += t3[w]*u0[j] + t3[5 + w]*u1[j] + t3[10 + w]*u2[j];
      }
      float* ob = outg + (size_t)b * 2560 + co*5;
      float flat[20];
      #pragma unroll
      for (int j = 0; j < 4; ++j)
        #pragma unroll
        for (int w = 0; w < 5; ++w) flat[j*5 + w] = acc[j][w];
      strow<20>(ob, flat);
    }
    __syncthreads();   // pool reuse boundary before next sample
  }
}

extern "C" void kernel_launch(void* const* d_in, const int* in_sizes, int n_in,
                              void* d_out, int out_size, void* d_ws, size_t ws_size,
                              hipStream_t stream) {
  (void)in_sizes; (void)n_in; (void)ws_size;
  const float* p[31];
  for (int i = 0; i < 31; ++i) p[i] = (const float*)d_in[i];
  float* ws = (float*)d_ws;

  transpose_w<<<(WT_TOTAL + 255) / 256, 256, 0, stream>>>(
      p[11] /*w1*/, p[17] /*wa*/, p[15] /*w2*/, p[21] /*w0*/,
      p[25] /*w0b2*/, p[27] /*w0c2*/, ws);

  int Btot = out_size / 2560;
  if (Btot <= 0) return;
  int nb = (Btot + 1) >> 1;
  fused_net<<<nb, 256, 0, stream>>>(
      p[0],
      p[1],  p[2],  p[3],  p[4],  p[5],  p[6],  p[7],  p[8],  p[9],  p[10],
      p[12],                 // b1
      p[13], p[14],          // wl1, bl1
      p[16],                 // b2
      p[18],                 // ba
      p[19], p[20],          // wra, bra
      p[22],                 // b0
      p[23], p[24],          // wl2, bl2
      p[26],                 // b0b2
      p[28],                 // b0c2
      p[29], p[30],          // wr02, br02
      ws + W1T_OFF, ws + WAT_OFF, ws + W2T_OFF, ws + W0T_OFF,
      ws + WB2T_OFF, ws + WC2T_OFF,
      (float*)d_out, Btot);
}

// Round 9
// 3074.799 us; speedup vs baseline: 1.4477x; 1.4477x over previous
//
#include <hip/hip_runtime.h>
#include <stdint.h>

// v8: algebraic FLOP cut on the proven v2 schedule.
// sl (last-axis matmul) commutes with conv (channel/height) in every
// relu(sl(conv(x))) chain -> apply sl FIRST:
//   s9: relu(conv_w0(sl_wl2(X2)))  1.53M -> 0.77M MACs
//   s7: relu(conv_w1(sl_wl1(X1)))  324K -> 172K
//   s3: relu(conv_w0a(sl_wl0(x)))  14K -> 4K
// Conv bias folds exactly: + bc[co]*S[o] + bsl[o], S[o]=sum_w wl[o,w]
// (S0/S1/S2 precomputed in transpose_w into ws tail).
// sl_nb passes ride along the existing T90/T2/T3 sl phases (same rows,
// two dot products per load). Total 5.34M -> 4.36M MACs/sample (-18%).
// Schedule = v2: 2 parallel samples/block, 256T, 80,896B LDS, 2 blk/CU.

#define WB2T_OFF 0        // w0b2: [k=ci*2+dh][512], 600*512 = 307200
#define WC2T_OFF 307200   // w0c2: [k=ci*3+dh][512], 375*512 = 192000
#define W0T_OFF  499200   // w0:   [k=ci*2+dh][300], 250*300 = 75000
#define W1T_OFF  574200   // w1:   [k=ci*2+dh][75],   50*75  = 3750
#define WAT_OFF  577950   // wa:   [k=ci*3+dh][125],  75*125 = 9375
#define W2T_OFF  587325   // w2:   [k=ci*2+dh][125], 150*125 = 18750
#define SUM0_OFF 606075   // S0[18] = rowsum(wl0)
#define SUM1_OFF 606093   // S1[10] = rowsum(wl1)
#define SUM2_OFF 606103   // S2[5]  = rowsum(wl2)
#define WT_TOTAL 606108

__global__ __launch_bounds__(256)
void transpose_w(const float* __restrict__ w1, const float* __restrict__ wa,
                 const float* __restrict__ w2, const float* __restrict__ w0,
                 const float* __restrict__ wb2, const float* __restrict__ wc2,
                 const float* __restrict__ wl0, const float* __restrict__ wl1,
                 const float* __restrict__ wl2,
                 float* __restrict__ ws) {
  int i = blockIdx.x * 256 + threadIdx.x;
  if (i < 3750) {                      // w1: M=75,  K=50
    int co = i / 50, k = i % 50;
    ws[W1T_OFF + k*75 + co] = w1[i];
  } else if (i < 13125) {              // wa: M=125, K=75
    int j = i - 3750; int co = j / 75, k = j % 75;
    ws[WAT_OFF + k*125 + co] = wa[j];
  } else if (i < 31875) {              // w2: M=125, K=150
    int j = i - 13125; int co = j / 150, k = j % 150;
    ws[W2T_OFF + k*125 + co] = w2[j];
  } else if (i < 106875) {             // w0: M=300, K=250
    int j = i - 31875; int co = j / 250, k = j % 250;
    ws[W0T_OFF + k*300 + co] = w0[j];
  } else if (i < 414075) {             // w0b2: M=512, K=600
    int j = i - 106875; int co = j / 600, k = j % 600;
    ws[WB2T_OFF + k*512 + co] = wb2[j];
  } else if (i < 606075) {             // w0c2: M=512, K=375
    int j = i - 414075; int co = j / 375, k = j % 375;
    ws[WC2T_OFF + k*512 + co] = wc2[j];
  } else if (i < 606093) {             // S0
    int j = i - 606075; float s = 0.f;
    for (int w = 0; w < 27; ++w) s += wl0[j*27 + w];
    ws[SUM0_OFF + j] = s;
  } else if (i < 606103) {             // S1
    int j = i - 606093; float s = 0.f;
    for (int w = 0; w < 18; ++w) s += wl1[j*18 + w];
    ws[SUM1_OFF + j] = s;
  } else if (i < 606108) {             // S2
    int j = i - 606103; float s = 0.f;
    for (int w = 0; w < 10; ++w) s += wl2[j*10 + w];
    ws[SUM2_OFF + j] = s;
  }
}

template<int N>
__device__ __forceinline__ void ldrow(float* r, const float* p) {
  #pragma unroll
  for (int i = 0; i < N/4; ++i) {
    float4 q = reinterpret_cast<const float4*>(p)[i];
    r[4*i+0] = q.x; r[4*i+1] = q.y; r[4*i+2] = q.z; r[4*i+3] = q.w;
  }
}
template<int N>
__device__ __forceinline__ void strow(float* p, const float* r) {
  #pragma unroll
  for (int i = 0; i < N/4; ++i) {
    float4 q; q.x = r[4*i+0]; q.y = r[4*i+1]; q.z = r[4*i+2]; q.w = r[4*i+3];
    reinterpret_cast<float4*>(p)[i] = q;
  }
}

// Per-sample pool (floats). Liveness (phases: s1 sl0 s2' s5 sl1 s7' s8m sl2 s9' s10):
//  X1  [0,2500)    (25c,5h,20)   s5..sl1
//  SX  [2500,2640) (5h,28)       s1..sl0
//  XS0 [2640,2740) (5h,20)       sl0..s2'
//  T90 [2740,2840) (5h,20)       sl0..s5
//  Z0SL[2840,3340) (25r,20)      s2'..s5
//  X1S [2500,4000) (25c,5h,12)   sl1..s7'  (over dead SX/XS0/T90/Z0SL)
//  Z1S [4500,8100) (75c,4h,12)   s7'..s8m
//  T2  [8100,9600) (25c,5h,12)   sl1..s8m
//  X2  [0,4500)    (125c,3h,12)  s8m..sl2  (over dead X1/X1S)
//  T3  [8100,10100)(125c,16)     sl2..s10  (over dead T2)
//  X2S [4500,7500) (125c,3h,8)   sl2..s9'  (over dead Z1S)
//  Z2S [0,3600)    (300co,12)    s9'..s10  (over dead X2)
#define POOL   10112
#define X1_O   0
#define SX_O   2500
#define XS0_O  2640
#define T90_O  2740
#define Z0SL_O 2840
#define X1S_O  2500
#define Z1S_O  4500
#define T2_O   8100
#define X2_O   0
#define T3_O   8100
#define X2S_O  4500
#define Z2S_O  0

__global__ __launch_bounds__(256, 2)
void fused_net(const float* __restrict__ xg,
  const float* __restrict__ w0a_, const float* __restrict__ b0a_,
  const float* __restrict__ wl0_, const float* __restrict__ bl0_,
  const float* __restrict__ w0b_, const float* __restrict__ b0b_,
  const float* __restrict__ w0c_, const float* __restrict__ b0c_,
  const float* __restrict__ wr0_, const float* __restrict__ br0_,
  const float* __restrict__ b1_,
  const float* __restrict__ wl1_, const float* __restrict__ bl1_,
  const float* __restrict__ b2_,
  const float* __restrict__ ba_,
  const float* __restrict__ wra_, const float* __restrict__ bra_,
  const float* __restrict__ b0_,
  const float* __restrict__ wl2_, const float* __restrict__ bl2_,
  const float* __restrict__ b0b2_,
  const float* __restrict__ b0c2_,
  const float* __restrict__ wr02_,const float* __restrict__ br02_,
  const float* __restrict__ w1t, const float* __restrict__ wat,
  const float* __restrict__ w2t, const float* __restrict__ w0t,
  const float* __restrict__ wb2t, const float* __restrict__ wc2t,
  const float* __restrict__ sums,
  float* __restrict__ outg, int Btot)
{
  __shared__ __align__(16) float S[2*POOL];   // 80,896 B -> 2 blocks/CU
  const int tid = threadIdx.x;
  const int b0 = blockIdx.x * 2;

  // ---- s1: load x (5h,27w) -> SX stride 28, both samples
  for (int i = tid; i < 270; i += 256) {
    int samp = i / 135, j = i % 135;
    int h = j / 27, w = j % 27;
    float v = 0.f;
    if (b0 + samp < Btot) v = xg[(size_t)(b0 + samp) * 135 + j];
    S[samp*POOL + SX_O + h*28 + w] = v;
  }
  __syncthreads();

  // ---- sl0: XS0 = sl_nb(x,wl0); T90 = sl(x,wr0)+br0. 30 tasks.
  if (tid < 30) {
    int samp = tid / 15, r = tid % 15, h = r / 3, o0 = (r % 3) * 6;
    float* P = S + samp*POOL;
    float row[28]; ldrow<28>(row, P + SX_O + h*28);
    float xs[6], t9[6];
    #pragma unroll
    for (int k = 0; k < 6; ++k) { xs[k] = 0.f; t9[k] = br0_[o0 + k]; }
    for (int w = 0; w < 27; ++w) {
      float rv = row[w];
      #pragma unroll
      for (int k = 0; k < 6; ++k) {
        xs[k] += rv * wl0_[(o0 + k)*27 + w];
        t9[k] += rv * wr0_[(o0 + k)*27 + w];
      }
    }
    #pragma unroll
    for (int k = 0; k < 6; ++k) {
      P[XS0_O + h*20 + o0 + k] = xs[k];
      P[T90_O + h*20 + o0 + k] = t9[k];
    }
  }
  __syncthreads();

  // ---- s2': Z0SL = relu(conv_nb w0a(XS0) + b0a*S0 + bl0). 50 tasks.
  if (tid < 50) {
    int samp = tid / 25, r = tid % 25, co = r / 5, h = r % 5;
    float* P = S + samp*POOL;
    float acc[20];
    float bc = b0a_[co];
    #pragma unroll
    for (int o = 0; o < 18; ++o) acc[o] = bc * sums[o] + bl0_[o];
    acc[18] = 0.f; acc[19] = 0.f;
    #pragma unroll
    for (int dh = 0; dh < 3; ++dh) {
      int hi = h + dh - 1;
      if (hi >= 0 && hi < 5) {
        float wf = w0a_[co*3 + dh];
        float row[20]; ldrow<20>(row, P + XS0_O + hi*20);
        #pragma unroll
        for (int o = 0; o < 18; ++o) acc[o] += row[o] * wf;
      }
    }
    #pragma unroll
    for (int o = 0; o < 18; ++o) acc[o] = fmaxf(acc[o], 0.f);
    strow<20>(P + Z0SL_O + (co*5 + h)*20, acc);
  }
  __syncthreads();

  // ---- s5: X1 = conv w0b(Z0SL) + b0b + (w0c*T90 + b0c). 250 tasks.
  if (tid < 250) {
    int samp = tid / 125, r = tid % 125, h = r / 25, co = r % 25;
    float* P = S + samp*POOL;
    float tr[20]; ldrow<20>(tr, P + T90_O + h*20);
    float wc = w0c_[co];
    float base = b0b_[co] + b0c_[co];
    float acc[20];
    #pragma unroll
    for (int o = 0; o < 18; ++o) acc[o] = base + tr[o]*wc;
    acc[18] = 0.f; acc[19] = 0.f;
    #pragma unroll
    for (int dh = 0; dh < 3; ++dh) {
      int hi = h + dh - 1;
      if (hi >= 0 && hi < 5) {
        #pragma unroll
        for (int ci = 0; ci < 5; ++ci) {
          float wgt = w0b_[(co*5 + ci)*3 + dh];
          float row[20]; ldrow<20>(row, P + Z0SL_O + (ci*5 + hi)*20);
          #pragma unroll
          for (int o = 0; o < 18; ++o) acc[o] += row[o] * wgt;
        }
      }
    }
    strow<20>(P + X1_O + (co*5 + h)*20, acc);
  }
  __syncthreads();

  // ---- sl1: T2 = sl(X1,wra)+bra; X1S = sl_nb(X1,wl1). 250 tasks.
  if (tid < 250) {
    int samp = tid / 125, r = tid % 125, h = r / 25, c = r % 25;
    float* P = S + samp*POOL;
    float row[20]; ldrow<20>(row, P + X1_O + (c*5 + h)*20);
    float t2[12], x1s[12];
    #pragma unroll
    for (int o = 0; o < 10; ++o) {
      float a = bra_[o], s = 0.f;
      #pragma unroll
      for (int w = 0; w < 18; ++w) {
        a += row[w] * wra_[o*18 + w];
        s += row[w] * wl1_[o*18 + w];
      }
      t2[o] = a; x1s[o] = s;
    }
    t2[10] = t2[11] = 0.f; x1s[10] = x1s[11] = 0.f;
    strow<12>(P + T2_O  + (c*5 + h)*12, t2);
    strow<12>(P + X1S_O + (c*5 + h)*12, x1s);
  }
  __syncthreads();

  // ---- s7': Z1S = relu(conv_nb w1(X1S) + b1*S1 + bl1). 300 tasks=(samp,co,h2).
  for (int t = tid; t < 300; t += 256) {
    int samp = t / 150, r = t % 150, co = r >> 1, h0 = (r & 1) * 2;
    float* P = S + samp*POOL;
    float acc[2][10];
    float bc = b1_[co];
    #pragma unroll
    for (int o = 0; o < 10; ++o) {
      float b = bc * sums[18 + o] + bl1_[o];
      acc[0][o] = b; acc[1][o] = b;
    }
    for (int ci = 0; ci < 25; ++ci) {
      float wx = w1t[(ci*2 + 0)*75 + co];
      float wy = w1t[(ci*2 + 1)*75 + co];
      float r0[12], r1[12], r2[12];
      ldrow<12>(r0, P + X1S_O + (ci*5 + h0    )*12);
      ldrow<12>(r1, P + X1S_O + (ci*5 + h0 + 1)*12);
      ldrow<12>(r2, P + X1S_O + (ci*5 + h0 + 2)*12);
      #pragma unroll
      for (int o = 0; o < 10; ++o) {
        acc[0][o] += r0[o]*wx + r1[o]*wy;
        acc[1][o] += r1[o]*wx + r2[o]*wy;
      }
    }
    #pragma unroll
    for (int hh = 0; hh < 2; ++hh) {
      float out[12];
      #pragma unroll
      for (int o = 0; o < 10; ++o) out[o] = fmaxf(acc[hh][o], 0.f);
      out[10] = 0.f; out[11] = 0.f;
      strow<12>(P + Z1S_O + (co*4 + h0 + hh)*12, out);
    }
  }
  __syncthreads();

  // ---- s8m: X2 = conv wa(T2) + conv w2(Z1S) + b2 + ba. 250 tasks=(samp,co).
  if (tid < 250) {
    int samp = tid / 125, co = tid % 125;
    float* P = S + samp*POOL;
    float acc[3][10];
    float bias = b2_[co] + ba_[co];
    #pragma unroll
    for (int h = 0; h < 3; ++h)
      #pragma unroll
      for (int w = 0; w < 10; ++w) acc[h][w] = bias;
    for (int ci = 0; ci < 25; ++ci) {          // conv wa over T2 (kh=3)
      float wf0 = wat[(ci*3 + 0)*125 + co];
      float wf1 = wat[(ci*3 + 1)*125 + co];
      float wf2 = wat[(ci*3 + 2)*125 + co];
      float rr[5][12];
      #pragma unroll
      for (int hh = 0; hh < 5; ++hh) ldrow<12>(rr[hh], P + T2_O + (ci*5 + hh)*12);
      #pragma unroll
      for (int h = 0; h < 3; ++h)
        #pragma unroll
        for (int w = 0; w < 10; ++w)
          acc[h][w] += rr[h][w]*wf0 + rr[h+1][w]*wf1 + rr[h+2][w]*wf2;
    }
    for (int ci = 0; ci < 75; ++ci) {          // conv w2 over Z1S (kh=2)
      float wx = w2t[(ci*2 + 0)*125 + co];
      float wy = w2t[(ci*2 + 1)*125 + co];
      float rr[4][12];
      #pragma unroll
      for (int hh = 0; hh < 4; ++hh) ldrow<12>(rr[hh], P + Z1S_O + (ci*4 + hh)*12);
      #pragma unroll
      for (int h = 0; h < 3; ++h)
        #pragma unroll
        for (int w = 0; w < 10; ++w)
          acc[h][w] += rr[h][w]*wx + rr[h+1][w]*wy;
    }
    #pragma unroll
    for (int h = 0; h < 3; ++h) {
      float out[12];
      #pragma unroll
      for (int w = 0; w < 10; ++w) out[w] = acc[h][w];
      out[10] = 0.f; out[11] = 0.f;
      strow<12>(P + X2_O + (co*3 + h)*12, out);
    }
  }
  __syncthreads();

  // ---- sl2: T3 = sl(X2,wr02)+br02; X2S = sl_nb(X2,wl2). 250 tasks.
  if (tid < 250) {
    int samp = tid / 125, c = tid % 125;
    float* P = S + samp*POOL;
    float rr[3][12];
    #pragma unroll
    for (int h = 0; h < 3; ++h) ldrow<12>(rr[h], P + X2_O + (c*3 + h)*12);
    float t3[16];
    #pragma unroll
    for (int h = 0; h < 3; ++h) {
      float x2s[8];
      #pragma unroll
      for (int o = 0; o < 5; ++o) {
        float a = br02_[o], s = 0.f;
        #pragma unroll
        for (int w = 0; w < 10; ++w) {
          a += rr[h][w] * wr02_[o*10 + w];
          s += rr[h][w] * wl2_[o*10 + w];
        }
        t3[h*5 + o] = a; x2s[o] = s;
      }
      x2s[5] = x2s[6] = x2s[7] = 0.f;
      strow<8>(P + X2S_O + (c*3 + h)*8, x2s);
    }
    t3[15] = 0.f;
    strow<16>(P + T3_O + c*16, t3);
  }
  __syncthreads();

  // ---- s9': Z2S = relu(conv_nb w0(X2S) + b0*S2 + bl2). 300 tasks=(samp,co-pair).
  for (int t = tid; t < 300; t += 256) {
    int samp = t / 150, q2 = t % 150, co = q2 * 2;
    float* P = S + samp*POOL;
    float acc[2][2][5];
    #pragma unroll
    for (int j = 0; j < 2; ++j) {
      float bc = b0_[co + j];
      #pragma unroll
      for (int o = 0; o < 5; ++o) {
        float b = bc * sums[28 + o] + bl2_[o];
        acc[j][0][o] = b; acc[j][1][o] = b;
      }
    }
    for (int ci = 0; ci < 125; ++ci) {
      float2 wxv = *reinterpret_cast<const float2*>(w0t + (ci*2 + 0)*300 + co);
      float2 wyv = *reinterpret_cast<const float2*>(w0t + (ci*2 + 1)*300 + co);
      float a0[8], a1[8], a2[8];
      ldrow<8>(a0, P + X2S_O + (ci*3 + 0)*8);
      ldrow<8>(a1, P + X2S_O + (ci*3 + 1)*8);
      ldrow<8>(a2, P + X2S_O + (ci*3 + 2)*8);
      float wx[2] = {wxv.x, wxv.y};
      float wy[2] = {wyv.x, wyv.y};
      #pragma unroll
      for (int j = 0; j < 2; ++j)
        #pragma unroll
        for (int o = 0; o < 5; ++o) {
          acc[j][0][o] += a0[o]*wx[j] + a1[o]*wy[j];
          acc[j][1][o] += a1[o]*wx[j] + a2[o]*wy[j];
        }
    }
    #pragma unroll
    for (int j = 0; j < 2; ++j) {
      float out[12];
      #pragma unroll
      for (int h = 0; h < 2; ++h)
        #pragma unroll
        for (int o = 0; o < 5; ++o) out[h*5 + o] = fmaxf(acc[j][h][o], 0.f);
      out[10] = 0.f; out[11] = 0.f;
      strow<12>(P + Z2S_O + (co + j)*12, out);
    }
  }
  __syncthreads();

  // ---- s10: out = conv w0b2(Z2S) + conv w0c2(T3). 256 tasks=(samp,co-quad).
  {
    int samp = tid >> 7, coq = tid & 127;
    int co = coq * 4;
    float* P = S + samp*POOL;
    float acc[4][5];
    #pragma unroll
    for (int j = 0; j < 4; ++j) {
      float bb = b0b2_[co + j] + b0c2_[co + j];
      #pragma unroll
      for (int w = 0; w < 5; ++w) acc[j][w] = bb;
    }
    for (int ci = 0; ci < 300; ++ci) {          // w0b2: kh=2
      float a[12]; ldrow<12>(a, P + Z2S_O + ci*12);
      float4 uxv = *reinterpret_cast<const float4*>(wb2t + (ci*2 + 0)*512 + co);
      float4 uyv = *reinterpret_cast<const float4*>(wb2t + (ci*2 + 1)*512 + co);
      float ux[4] = {uxv.x, uxv.y, uxv.z, uxv.w};
      float uy[4] = {uyv.x, uyv.y, uyv.z, uyv.w};
      #pragma unroll
      for (int j = 0; j < 4; ++j)
        #pragma unroll
        for (int w = 0; w < 5; ++w)
          acc[j][w] += a[w]*ux[j] + a[5 + w]*uy[j];
    }
    for (int ci = 0; ci < 125; ++ci) {          // w0c2: kh=3
      float t3[16]; ldrow<16>(t3, P + T3_O + ci*16);
      float4 u0v = *reinterpret_cast<const float4*>(wc2t + (ci*3 + 0)*512 + co);
      float4 u1v = *reinterpret_cast<const float4*>(wc2t + (ci*3 + 1)*512 + co);
      float4 u2v = *reinterpret_cast<const float4*>(wc2t + (ci*3 + 2)*512 + co);
      float u0[4] = {u0v.x, u0v.y, u0v.z, u0v.w};
      float u1[4] = {u1v.x, u1v.y, u1v.z, u1v.w};
      float u2[4] = {u2v.x, u2v.y, u2v.z, u2v.w};
      #pragma unroll
      for (int j = 0; j < 4; ++j)
        #pragma unroll
        for (int w = 0; w < 5; ++w)
          acc[j][w] += t3[w]*u0[j] + t3[5 + w]*u1[j] + t3[10 + w]*u2[j];
    }
    if (b0 + samp < Btot) {
      float* ob = outg + (size_t)(b0 + samp) * 2560 + co*5;
      float flat[20];
      #pragma unroll
      for (int j = 0; j < 4; ++j)
        #pragma unroll
        for (int w = 0; w < 5; ++w) flat[j*5 + w] = acc[j][w];
      strow<20>(ob, flat);
    }
  }
}

extern "C" void kernel_launch(void* const* d_in, const int* in_sizes, int n_in,
                              void* d_out, int out_size, void* d_ws, size_t ws_size,
                              hipStream_t stream) {
  (void)in_sizes; (void)n_in; (void)ws_size;
  const float* p[31];
  for (int i = 0; i < 31; ++i) p[i] = (const float*)d_in[i];
  float* ws = (float*)d_ws;

  transpose_w<<<(WT_TOTAL + 255) / 256, 256, 0, stream>>>(
      p[11] /*w1*/, p[17] /*wa*/, p[15] /*w2*/, p[21] /*w0*/,
      p[25] /*w0b2*/, p[27] /*w0c2*/,
      p[3] /*wl0*/, p[13] /*wl1*/, p[23] /*wl2*/, ws);

  int Btot = out_size / 2560;
  if (Btot <= 0) return;
  int nb = (Btot + 1) >> 1;
  fused_net<<<nb, 256, 0, stream>>>(
      p[0],
      p[1],  p[2],  p[3],  p[4],  p[5],  p[6],  p[7],  p[8],  p[9],  p[10],
      p[12],                 // b1
      p[13], p[14],          // wl1, bl1
      p[16],                 // b2
      p[18],                 // ba
      p[19], p[20],          // wra, bra
      p[22],                 // b0
      p[23], p[24],          // wl2, bl2
      p[26],                 // b0b2
      p[28],                 // b0c2
      p[29], p[30],          // wr02, br02
      ws + W1T_OFF, ws + WAT_OFF, ws + W2T_OFF, ws + W0T_OFF,
      ws + WB2T_OFF, ws + WC2T_OFF,
      ws + SUM0_OFF,
      (float*)d_out, Btot);
}